// Round 5
// baseline (889.007 us; speedup 1.0000x reference)
//
#include <hip/hip_runtime.h>

// Problem constants (B=8, S=2048, D=1024, H=4096, E=8, CAP_FACTOR=1.5)
#define NTOK 16384
#define DDIM 1024
#define EEXP 8
#define HDIM 4096
#define CAP  3072               // int(1.5 * 16384 / 8)
#define ECAP (EEXP*CAP)         // 24576

// Workspace layout (bytes)
#define OFF_GATE 0u                          // float[NTOK]
#define OFF_GIDX 65536u                      // int[NTOK]
#define OFF_SLOT 131072u                     // int[NTOK]
#define OFF_TOS  196608u                     // int[ECAP]
#define OFF_CNT  294912u                     // int[8]
#define OFF_PIMP 294976u                     // float[4096*8]
#define OFF_PFX  430080u                     // int[9] compact-tile prefix (128-row tiles)
#define OFF_XBF  1048576u                    // ushort[NTOK*DDIM]       (32 MB) row-major
#define OFF_W1T  34603008u                   // ushort[E*HDIM*DDIM]     (64 MB) k-tiled image
#define OFF_W2T  101711872u                  // ushort[E*DDIM*HDIM]     (64 MB) k-tiled image
#define OFF_HB   168820736u                  // ushort[ECAP*HDIM]       (192 MB) k-tiled image
#define WS_NEED  370147328u

typedef float f32x4  __attribute__((ext_vector_type(4)));
typedef short bf16x8 __attribute__((ext_vector_type(8)));
typedef unsigned short u16x8 __attribute__((ext_vector_type(8)));

__device__ __forceinline__ unsigned short f2bf(float f){
  unsigned int u = __float_as_uint(f);
  unsigned int r = (u + 0x7fffu + ((u >> 16) & 1u)) >> 16;   // RNE
  return (unsigned short)r;
}
__device__ __forceinline__ float siluf(float v){ return v/(1.0f+__expf(-v)); }

// async global->LDS, 16B per lane; LDS dst must be wave-uniform base (+lane*16 implicit)
__device__ __forceinline__ void gl16(const void* g, void* l){
  __builtin_amdgcn_global_load_lds((const __attribute__((address_space(1))) unsigned int*)g,
                                   (__attribute__((address_space(3))) unsigned int*)l,
                                   16, 0, 0);
}

// ---------------------------------------------------------------------------
// K-tiled LDS-image layout helpers.
// A step-tile image (one [128 rows][32 k] bf16 tile = 8 KB) stores, at byte
// offset row*64 + chunk'*16, the 8 k-elements of chunk = chunk' ^ ((row>>1)&3)
// (the bank-spreading involution the ffn's ds_read expects). Panels:
// Wt[e][n>>7][k>>5] and hbf[slot>>7][h>>5], each panel 8 KB, fully linear —
// so the GEMM stages one contiguous 8 KB stream per operand per K-step.
// ---------------------------------------------------------------------------

// ---------------------------------------------------------------------------
// Router: one wave per token. Also emits x in bf16 (fused conversion).
// ---------------------------------------------------------------------------
__global__ __launch_bounds__(256) void router_kernel(
    const float* __restrict__ x, const float* __restrict__ Wr,
    const float* __restrict__ br, float* __restrict__ gate_value,
    int* __restrict__ gate_idx, float* __restrict__ partial_imp,
    unsigned short* __restrict__ xbf)
{
  __shared__ float pbuf[4][8];
  const int wave = threadIdx.x >> 6;
  const int lane = threadIdx.x & 63;
  const int n = blockIdx.x*4 + wave;
  float acc[8];
#pragma unroll
  for (int e=0;e<8;e++) acc[e]=0.0f;
  const float* xr = x + (size_t)n*DDIM;
  unsigned short* xbr = xbf + (size_t)n*DDIM;
#pragma unroll
  for (int k=0;k<16;k++){
    const int d = k*64 + lane;
    const float xv = xr[d];
    xbr[d] = f2bf(xv);
    const float4 w0 = ((const float4*)(Wr + (size_t)d*8))[0];
    const float4 w1 = ((const float4*)(Wr + (size_t)d*8))[1];
    acc[0] += xv*w0.x; acc[1] += xv*w0.y; acc[2] += xv*w0.z; acc[3] += xv*w0.w;
    acc[4] += xv*w1.x; acc[5] += xv*w1.y; acc[6] += xv*w1.z; acc[7] += xv*w1.w;
  }
#pragma unroll
  for (int e=0;e<8;e++){
    acc[e] += __shfl_xor(acc[e], 32, 64);
    acc[e] += __shfl_xor(acc[e], 16, 64);
    acc[e] += __shfl_xor(acc[e],  8, 64);
    acc[e] += __shfl_xor(acc[e],  4, 64);
    acc[e] += __shfl_xor(acc[e],  2, 64);
    acc[e] += __shfl_xor(acc[e],  1, 64);
  }
  if (lane==0){
    float lg[8];
    float mx = -3.4e38f;
    int bi = 0;
#pragma unroll
    for (int e=0;e<8;e++) lg[e] = acc[e] + br[e];
#pragma unroll
    for (int e=0;e<8;e++){ if (lg[e] > mx){ mx = lg[e]; bi = e; } }
    float s = 0.f;
#pragma unroll
    for (int e=0;e<8;e++){ lg[e] = __expf(lg[e]-mx); s += lg[e]; }
    const float inv = 1.0f/s;
    gate_value[n] = inv;
    gate_idx[n] = bi;
#pragma unroll
    for (int e=0;e<8;e++) pbuf[wave][e] = lg[e]*inv;
  }
  __syncthreads();
  if (threadIdx.x < 8){
    partial_imp[(size_t)blockIdx.x*8 + threadIdx.x] =
      pbuf[0][threadIdx.x]+pbuf[1][threadIdx.x]+pbuf[2][threadIdx.x]+pbuf[3][threadIdx.x];
  }
}

// ---------------------------------------------------------------------------
// Scan: FIFO positions per expert (single block) + aux losses + compact-tile
// prefix pfx[9] (128-row tiles per expert) for balanced ffn grids.
// ---------------------------------------------------------------------------
__global__ __launch_bounds__(256) void scan_kernel(
    const int* __restrict__ gate_idx, const float* __restrict__ partial_imp,
    int* __restrict__ slot_or_neg, int* __restrict__ tok_of_slot,
    int* __restrict__ cnt, int* __restrict__ pfx, float* __restrict__ out_losses)
{
  __shared__ int hist[256][8];
  __shared__ float impbuf[32][8];
  const int t = threadIdx.x;
  int h[8];
#pragma unroll
  for (int e=0;e<8;e++) h[e]=0;
  const int base = t*64;
  for (int i=0;i<64;i++) h[gate_idx[base+i]]++;
#pragma unroll
  for (int e=0;e<8;e++) hist[t][e]=h[e];
  {
    const int e = t & 7, c = t >> 3;
    float s = 0.f;
    for (int r=c; r<4096; r+=32) s += partial_imp[(size_t)r*8+e];
    impbuf[c][e] = s;
  }
  __syncthreads();
  if (t < 8){
    int run = 0;
    for (int i=0;i<256;i++){ int v = hist[i][t]; hist[i][t] = run; run += v; }
    cnt[t] = run < CAP ? run : CAP;
  }
  __syncthreads();
#pragma unroll
  for (int e=0;e<8;e++) h[e]=hist[t][e];
  for (int i=0;i<64;i++){
    const int n = base+i;
    const int e = gate_idx[n];
    const int p = h[e]++;
    if (p < CAP){ const int s = e*CAP+p; slot_or_neg[n]=s; tok_of_slot[s]=n; }
    else slot_or_neg[n] = -1;
  }
  if (t==0){
    float imp[8]; float m = 0.f;
    for (int e=0;e<8;e++){ float s=0.f; for (int c=0;c<32;c++) s+=impbuf[c][e]; imp[e]=s; m+=s; }
    m *= 0.125f;
    float var = 0.f;
    for (int e=0;e<8;e++){ const float d=imp[e]-m; var += d*d; }
    var *= 0.125f;
    out_losses[0] = 1.0f;
    out_losses[1] = var/(m*m);
    // compact active-tile prefix (128-row tiles)
    int run = 0;
    pfx[0] = 0;
    for (int e=0;e<8;e++){ run += (cnt[e] + 127) >> 7; pfx[e+1] = run; }
  }
}

// ---------------------------------------------------------------------------
// Weight transpose + fp32->bf16 into the k-tiled pre-swizzled LDS image,
// both W1 and W2 in one launch. W [E][K][N] -> panels Wt[e][n>>7][k>>5],
// panel = [row=n&127][chunk'][8] with chunk' = ((k>>3)&3) ^ ((n>>1)&3).
// ---------------------------------------------------------------------------
__global__ __launch_bounds__(256) void cvt_w_t(
    const float* __restrict__ W1, const float* __restrict__ W2,
    unsigned short* __restrict__ W1t, unsigned short* __restrict__ W2t)
{
  __shared__ float t[64][65];
  const bool second = blockIdx.z >= 8;
  const int e = second ? (int)blockIdx.z - 8 : (int)blockIdx.z;
  const float* W = second ? W2 : W1;
  unsigned short* Wt = second ? W2t : W1t;
  const int K = second ? HDIM : DDIM;
  const int N = second ? DDIM : HDIM;
  const int nt = second ? (int)blockIdx.y : (int)blockIdx.x;
  const int kt = second ? (int)blockIdx.x : (int)blockIdx.y;
  const int n0 = nt*64, k0 = kt*64;

  const int lr = threadIdx.x >> 4;          // 0..15
  const int lc = (threadIdx.x & 15) * 4;    // 0..60
#pragma unroll
  for (int i=0;i<4;i++){
    const int r = i*16 + lr;
    const float4 v = *(const float4*)(W + ((size_t)e*K + k0 + r)*N + n0 + lc);
    t[r][lc+0]=v.x; t[r][lc+1]=v.y; t[r][lc+2]=v.z; t[r][lc+3]=v.w;
  }
  __syncthreads();
  const int sr = threadIdx.x >> 3;          // 0..31 (n-row within half)
  const int sc = (threadIdx.x & 7) * 8;     // 0..56 (k offset, 8-aligned)
#pragma unroll
  for (int i=0;i<2;i++){
    const int r = i*32 + sr;
    u16x8 o;
#pragma unroll
    for (int j=0;j<8;j++) o[j] = f2bf(t[sc+j][r]);
    const int n_ = n0 + r;                  // global n (output row)
    const int k_ = k0 + sc;                 // global k (8-aligned)
    const size_t idx = ((((size_t)e*(N>>7) + (n_>>7))*(K>>5) + (k_>>5))<<12)
                     + (size_t)((n_&127)<<5)
                     + (size_t)(((((k_>>3)&3) ^ ((n_>>1)&3)))<<3);
    *(u16x8*)(Wt + idx) = o;
  }
}

// ---------------------------------------------------------------------------
// MFMA grouped FFN GEMM (verified round-2 body): 128x128 tile, BK=32 bf16,
// 4 waves, each wave 64x64 via 4x4 of v_mfma_f32_16x16x32_bf16.
// Single-buffer 2-barrier K-loop (unchanged schedule).
//
// THIS ROUND'S change: B (both phases) and A (phase 2) are staged from
// k-tiled pre-swizzled panel images -> each K-step's gl16 set is one
// CONTIGUOUS 8 KB stream per operand (identity copy into LDS), replacing
// the 64B-granule strided gathers that capped service at ~2.5 TB/s.
// Phase-1 A remains the per-token gather (row-major xbf, swizzled chunk).
//
// Compact grid via pfx (128-row tiles), coltile fastest.
// PHASE 1: hbf(image) = bf16(silu(Xg @ W1' + b1));
// PHASE 2: out[tok] = (h @ W2' + b2)*gate
// ---------------------------------------------------------------------------
template<int PHASE>
__global__ __launch_bounds__(256) void ffn_mfma(
    const unsigned short* __restrict__ A,   // PHASE1: xbf row-major; PHASE2: hbf image
    const unsigned short* __restrict__ Bt,  // k-tiled panel image
    const float* __restrict__ bias,         // [E][NN]
    const int* __restrict__ tok_of_slot,
    const int* __restrict__ cnt,
    const int* __restrict__ pfx,
    const float* __restrict__ gate_value,
    void* __restrict__ Out)
{
  constexpr int K   = (PHASE==1)? DDIM : HDIM;
  constexpr int NN  = (PHASE==1)? HDIM : DDIM;
  constexpr int NCT = NN/128;               // 32 or 8 coltiles

  // ---- compact work mapping (coltile fastest)
  int p[9];
#pragma unroll
  for (int i=0;i<9;i++) p[i] = pfx[i];
  const int bid = blockIdx.x;
  const int ct = bid / NCT;
  const int coltile = bid - ct*NCT;
  if (ct >= p[8]) return;
  int e = 0;
#pragma unroll
  for (int i=1;i<8;i++) e += (ct >= p[i]);
  const int r0 = (ct - p[e])*128;
  const int ce = cnt[e];
  const int slotbase = e*CAP + r0;          // 128-aligned

  __shared__ alignas(16) char smem[16384];
  char* As  = smem;
  char* Bsm = smem + 8192;

  const int tid  = threadIdx.x;
  const int l    = tid & 63;
  const int wv   = __builtin_amdgcn_readfirstlane(tid >> 6);

  // ---- A staging addresses
  // PHASE1: gathered rows (row-major xbf, pre-swizzled source chunk)
  // PHASE2: linear panel stream (identity copy)
  const int sub = l >> 2;                   // 0..15
  const int c   = l & 3;
  const int gr0 = wv*16 + sub;              // tile rows 0..63
  const int gr1 = 64 + gr0;                 // tile rows 64..127

  const char *agp0, *agp1;
  if (PHASE==1){
    const int kg0 = c ^ ((gr0>>1)&3);
    const int kg1 = c ^ ((gr1>>1)&3);
    const int t0 = (r0 + gr0 < ce) ? tok_of_slot[slotbase + gr0] : 0;
    const int t1 = (r0 + gr1 < ce) ? tok_of_slot[slotbase + gr1] : 0;
    agp0 = (const char*)(A + (size_t)t0*K) + kg0*16;
    agp1 = (const char*)(A + (size_t)t1*K) + kg1*16;
    // per step k0 (elems): advance k0*2 bytes within the row
  } else {
    const char* apan = (const char*)A + ((size_t)(slotbase>>7)*(K>>5))*8192;
    agp0 = apan + wv*1024 + l*16;
    agp1 = apan + 4096 + wv*1024 + l*16;
    // per step: advance (k0/32)*8192 bytes
  }
  const char* bpan = (const char*)Bt + (((size_t)e*NCT + coltile)*(K>>5))*8192;
  const char* bgp0 = bpan + wv*1024 + l*16;
  const char* bgp1 = bpan + 4096 + wv*1024 + l*16;

  char* a_dst0 = As  + wv*1024;  char* a_dst1 = As  + 4096 + wv*1024;
  char* b_dst0 = Bsm + wv*1024;  char* b_dst1 = Bsm + 4096 + wv*1024;

  // ---- fragment read offsets (image: row*64 + (kgf^((row>>1)&3))*16)
  const int wrow = (wv & 1)*64, wcol = (wv >> 1)*64;
  const int lm  = l & 15;
  const int kgf = l >> 4;                   // 0..3
  int aoff[4], bofs[4];
#pragma unroll
  for (int i=0;i<4;i++){
    const int ra = wrow + i*16 + lm;
    aoff[i] = ra*64 + ((kgf ^ ((ra>>1)&3))*16);
    const int rb = wcol + i*16 + lm;
    bofs[i] = rb*64 + ((kgf ^ ((rb>>1)&3))*16);
  }

  f32x4 acc[4][4];
#pragma unroll
  for (int i=0;i<4;i++)
#pragma unroll
    for (int j=0;j<4;j++) acc[i][j] = (f32x4){0.f,0.f,0.f,0.f};

  for (int k0 = 0; k0 < K; k0 += 32){
    __syncthreads();                        // prev iter done reading LDS
    if (PHASE==1){
      gl16(agp0 + k0*2, a_dst0);
      gl16(agp1 + k0*2, a_dst1);
    } else {
      const size_t toff = (size_t)(k0>>5)*8192;
      gl16(agp0 + toff, a_dst0);
      gl16(agp1 + toff, a_dst1);
    }
    {
      const size_t toff = (size_t)(k0>>5)*8192;
      gl16(bgp0 + toff, b_dst0);
      gl16(bgp1 + toff, b_dst1);
    }
    __syncthreads();                        // drains vmcnt -> staging visible
    bf16x8 af[4], bfr[4];
#pragma unroll
    for (int i=0;i<4;i++) af[i]  = *(const bf16x8*)(As  + aoff[i]);
#pragma unroll
    for (int i=0;i<4;i++) bfr[i] = *(const bf16x8*)(Bsm + bofs[i]);
#pragma unroll
    for (int mi=0;mi<4;mi++)
#pragma unroll
      for (int ni=0;ni<4;ni++)
        acc[mi][ni] = __builtin_amdgcn_mfma_f32_16x16x32_bf16(af[mi], bfr[ni], acc[mi][ni], 0, 0, 0);
  }

  // ---- epilogue. C/D layout: col = lane&15, row = (lane>>4)*4 + reg
  const float* bp = bias + (size_t)e*NN + coltile*128 + wcol;
  float bv[4];
#pragma unroll
  for (int ni=0;ni<4;ni++) bv[ni] = bp[ni*16 + lm];

  if (PHASE==1){
    // write hbf in k-tiled image form: panel (slot>>7, h>>5), slotbase 128-aligned
    unsigned short* hb = (unsigned short*)Out;
    const size_t rtbase = ((size_t)(slotbase>>7) * (HDIM>>5)) << 12;
#pragma unroll
    for (int mi=0;mi<4;mi++){
#pragma unroll
      for (int r=0;r<4;r++){
        const int row = wrow + mi*16 + kgf*4 + r;   // 0..127 == rr
        const int swr = (row>>1)&3;
        unsigned short* hrow = hb + rtbase + (size_t)(row<<5);
#pragma unroll
        for (int ni=0;ni<4;ni++){
          const int col = coltile*128 + wcol + ni*16 + lm;
          const float v = acc[mi][ni][r] + bv[ni];
          const size_t idx = ((size_t)(col>>5)<<12)
                           + (size_t)((((col>>3)&3) ^ swr)<<3) + (col&7);
          hrow[idx] = f2bf(siluf(v));
        }
      }
    }
  } else {
    float* op = (float*)Out;
#pragma unroll
    for (int mi=0;mi<4;mi++){
#pragma unroll
      for (int r=0;r<4;r++){
        const int row = wrow + mi*16 + kgf*4 + r;
        if (r0 + row < ce){
          const int tok = tok_of_slot[slotbase + row];
          const float g = gate_value[tok];
          float* orow = op + (size_t)tok*NN + coltile*128 + wcol;
#pragma unroll
          for (int ni=0;ni<4;ni++)
            orow[ni*16 + lm] = (acc[mi][ni][r] + bv[ni])*g;
        }
      }
    }
  }
}

// ---------------------------------------------------------------------------
// Dropped tokens pass through: out[n] = x[n] * gate[n]. One wave per token.
// ---------------------------------------------------------------------------
__global__ __launch_bounds__(256) void passthrough_kernel(
    const float* __restrict__ x, const int* __restrict__ slot_or_neg,
    const float* __restrict__ gate_value, float* __restrict__ out)
{
  const int wave = threadIdx.x >> 6;
  const int lane = threadIdx.x & 63;
  const int n = blockIdx.x*4 + wave;
  if (slot_or_neg[n] >= 0) return;
  const float g = gate_value[n];
#pragma unroll
  for (int k=0;k<4;k++){
    const int d = (k*64 + lane)*4;
    float4 v = *(const float4*)(x + (size_t)n*DDIM + d);
    v.x*=g; v.y*=g; v.z*=g; v.w*=g;
    *(float4*)(out + (size_t)n*DDIM + d) = v;
  }
}

extern "C" void kernel_launch(void* const* d_in, const int* in_sizes, int n_in,
                              void* d_out, int out_size, void* d_ws, size_t ws_size,
                              hipStream_t stream)
{
  const float* x  = (const float*)d_in[0];
  const float* Wr = (const float*)d_in[1];
  const float* br = (const float*)d_in[2];
  const float* W1 = (const float*)d_in[3];
  const float* b1 = (const float*)d_in[4];
  const float* W2 = (const float*)d_in[5];
  const float* b2 = (const float*)d_in[6];
  float* out = (float*)d_out;

  char* ws = (char*)d_ws;
  float*          gate_value  = (float*)(ws + OFF_GATE);
  int*            gate_idx    = (int*)  (ws + OFF_GIDX);
  int*            slot_or_neg = (int*)  (ws + OFF_SLOT);
  int*            tok_of_slot = (int*)  (ws + OFF_TOS);
  int*            cnt         = (int*)  (ws + OFF_CNT);
  int*            pfx         = (int*)  (ws + OFF_PFX);
  float*          partial_imp = (float*)(ws + OFF_PIMP);
  unsigned short* xbf         = (unsigned short*)(ws + OFF_XBF);
  unsigned short* W1t         = (unsigned short*)(ws + OFF_W1T);
  unsigned short* W2t         = (unsigned short*)(ws + OFF_W2T);
  unsigned short* hbf         = (unsigned short*)(ws + OFF_HB);

  // weight transpose+convert into k-tiled images (independent of router/scan)
  cvt_w_t<<<dim3(64, 16, 16), 256, 0, stream>>>(W1, W2, W1t, W2t);

  router_kernel<<<NTOK/4, 256, 0, stream>>>(x, Wr, br, gate_value, gate_idx,
                                            partial_imp, xbf);
  scan_kernel<<<1, 256, 0, stream>>>(gate_idx, partial_imp, slot_or_neg, tok_of_slot,
                                     cnt, pfx, out + (size_t)NTOK*DDIM);

  ffn_mfma<1><<<dim3((ECAP/128)*(HDIM/128)), 256, 0, stream>>>(
      xbf, W1t, b1, tok_of_slot, cnt, pfx, gate_value, (void*)hbf);
  ffn_mfma<2><<<dim3((ECAP/128)*(DDIM/128)), 256, 0, stream>>>(
      hbf, W2t, b2, tok_of_slot, cnt, pfx, gate_value, (void*)out);

  passthrough_kernel<<<NTOK/4, 256, 0, stream>>>(x, slot_or_neg, gate_value, out);
}